// Round 7
// baseline (405.933 us; speedup 1.0000x reference)
//
#include <hip/hip_runtime.h>
#include <stdint.h>

// ---------------------------------------------------------------------------
// Types / helpers
// ---------------------------------------------------------------------------
typedef __bf16 bf16x8 __attribute__((ext_vector_type(8)));
typedef float  f32x4  __attribute__((ext_vector_type(4)));

__device__ __forceinline__ unsigned short f2bf(float f) {
  union { float f; unsigned int u; } a; a.f = f;
  unsigned int r = a.u + 0x7FFFu + ((a.u >> 16) & 1u);   // RNE
  return (unsigned short)(r >> 16);
}

__device__ __forceinline__ unsigned short f2bf_fast(float f) {
  union { __bf16 b; unsigned short u; } v; v.b = (__bf16)f; return v.u;
}

// async global->LDS, 16B per lane. LDS dest must be wave-uniform base + lane*16.
__device__ __forceinline__ void cp16(const void* g, void* l) {
  auto g1 = reinterpret_cast<__attribute__((address_space(1))) unsigned int*>(
      reinterpret_cast<uintptr_t>(g));
  auto l3 = reinterpret_cast<__attribute__((address_space(3))) unsigned int*>(
      reinterpret_cast<uintptr_t>(l));
  __builtin_amdgcn_global_load_lds(g1, l3, 16, 0, 0);
}

// ---------------------------------------------------------------------------
// Weight fp32 -> bf16 MFMA-fragment-major layout, one launch for all 4 mats.
// Frag layout: tile (nt64, kt) of 64x64; elem addr =
//   ((nt64*Kt + kt)*8 + ks*4 + j)*512 + lane*8 + e
// holding W[nt64*64 + j*16 + (lane&15)][kt*64 + ks*32 + (lane>>4)*8 + e].
// A GEMM wave then loads frag (ks,j) as ONE coalesced dwordx4 per lane.
// ---------------------------------------------------------------------------
__global__ __launch_bounds__(256) void cvt_frag(
    const float* __restrict__ ipw, const float* __restrict__ outw,
    const float* __restrict__ w1, const float* __restrict__ w2,
    unsigned short* __restrict__ f_ipw, unsigned short* __restrict__ f_outw,
    unsigned short* __restrict__ f_w1, unsigned short* __restrict__ f_w2) {
  __shared__ unsigned short Ls[64][72];           // +8 pad: conflict-free phases
  const int b = blockIdx.x;
  const float* src; unsigned short* dst; int Kt, local;
  if (b < 768)       { src = ipw;  dst = f_ipw;  Kt = 16; local = b; }
  else if (b < 1024) { src = outw; dst = f_outw; Kt = 16; local = b - 768; }
  else if (b < 2048) { src = w1;   dst = f_w1;   Kt = 16; local = b - 1024; }
  else               { src = w2;   dst = f_w2;   Kt = 64; local = b - 2048; }
  const int tn = local / Kt, tk = local % Kt;
  const int K = Kt << 6;
  const int t = threadIdx.x;
  const int r = t >> 2, cb = (t & 3) << 4;       // row 0..63, col base 0/16/32/48
  const float* gp = src + (size_t)(tn * 64 + r) * K + tk * 64 + cb;
  #pragma unroll
  for (int u = 0; u < 4; u++) {
    float4 v = *(const float4*)(gp + u * 4);
    Ls[r][cb + u*4 + 0] = f2bf(v.x);
    Ls[r][cb + u*4 + 1] = f2bf(v.y);
    Ls[r][cb + u*4 + 2] = f2bf(v.z);
    Ls[r][cb + u*4 + 3] = f2bf(v.w);
  }
  __syncthreads();
  unsigned short* tile_dst = dst + (size_t)(tn * Kt + tk) * 4096;
  #pragma unroll
  for (int u = 0; u < 2; u++) {
    const int cid = t + u * 256;                 // (ks*4+j)*64 + lane
    const int lane = cid & 63, j = (cid >> 6) & 3, ks = cid >> 8;
    const int row = j * 16 + (lane & 15), col = ks * 32 + (lane >> 4) * 8;
    union { unsigned short u16[8]; uint4 v; } o;
    #pragma unroll
    for (int e = 0; e < 8; e++) o.u16[e] = Ls[row][col + e];
    *(uint4*)(tile_dst + cid * 8) = o.v;
  }
}

// ---------------------------------------------------------------------------
// LayerNorm (E=1024), fp32 in -> bf16 out, PLUS seeds the next split-K GEMM's
// accumulator: seed_out[row,:] = x[row,:] + seed_bias[:].
// ---------------------------------------------------------------------------
__global__ __launch_bounds__(256) void ln_bf16_seed(
    const float* __restrict__ x,
    const float* __restrict__ g,
    const float* __restrict__ bta,
    unsigned short* __restrict__ out,
    const float* __restrict__ seed_bias,
    float* __restrict__ seed_out) {
  const int row = blockIdx.x, t = threadIdx.x;
  const float4 v = *(const float4*)(x + (size_t)row * 1024 + t * 4);
  {
    float4 sb = *(const float4*)(seed_bias + t * 4);
    float4 sv;
    sv.x = v.x + sb.x; sv.y = v.y + sb.y; sv.z = v.z + sb.z; sv.w = v.w + sb.w;
    *(float4*)(seed_out + (size_t)row * 1024 + t * 4) = sv;
  }
  float s1 = v.x + v.y + v.z + v.w;
  float s2 = v.x*v.x + v.y*v.y + v.z*v.z + v.w*v.w;
  #pragma unroll
  for (int off = 1; off < 64; off <<= 1) {
    s1 += __shfl_xor(s1, off, 64);
    s2 += __shfl_xor(s2, off, 64);
  }
  __shared__ float r1[4], r2[4];
  if ((t & 63) == 0) { r1[t >> 6] = s1; r2[t >> 6] = s2; }
  __syncthreads();
  s1 = r1[0] + r1[1] + r1[2] + r1[3];
  s2 = r2[0] + r2[1] + r2[2] + r2[3];
  const float mean = s1 * (1.0f / 1024.0f);
  const float var  = s2 * (1.0f / 1024.0f) - mean * mean;
  const float rstd = rsqrtf(var + 1e-5f);
  const float4 gv = *(const float4*)(g + t * 4);
  const float4 bv = *(const float4*)(bta + t * 4);
  union { unsigned short u[4]; uint2 p; } o;
  o.u[0] = f2bf((v.x - mean) * rstd * gv.x + bv.x);
  o.u[1] = f2bf((v.y - mean) * rstd * gv.y + bv.y);
  o.u[2] = f2bf((v.z - mean) * rstd * gv.z + bv.z);
  o.u[3] = f2bf((v.w - mean) * rstd * gv.w + bv.w);
  *(uint2*)(out + (size_t)row * 1024 + t * 4) = o.p;
}

// ---------------------------------------------------------------------------
// GEMM core: A staged via cp16 into double-buffered LDS (2 x 16 KB only);
// B (weights) loaded directly global->VGPR from frag-major layout, coalesced,
// double-buffered one K-tile ahead. Steady-state waits: manual vmcnt(12)
// before the barrier (A-batch it done; A(it+1) + B(it+1) stay in flight),
// compiler inserts ~vmcnt(12) for B-use. No vmcnt(0) until the tail.
// MODE 0 = bf16 v+bias; MODE 2 = bf16 relu(v+bias); MODE 4 = atomic fp32 += v.
// ---------------------------------------------------------------------------
template <int MODE>
__device__ __forceinline__ void gemm_core(
    const unsigned short* __restrict__ A,
    const unsigned short* __restrict__ Bf,     // frag-major weights
    const float* __restrict__ bias,
    void* __restrict__ outp,
    int N, int K, int kbeg, int kend,
    unsigned short* As) {                      // 2 * 8192 elems
  const int tid = threadIdx.x;
  const int wave = tid >> 6, lane = tid & 63;
  const int q = lane >> 4, c = lane & 15;
  const int wm = (wave & 1) << 6, wn = (wave >> 1) << 6;
  const int m0 = blockIdx.x << 7, n0 = blockIdx.y << 7;

  const int srow = tid >> 3;                       // 0..31
  const int cg8  = ((tid & 7) ^ (srow & 7)) << 3;  // swizzled col chunk
  const unsigned short* gA = A + (size_t)(m0 + srow) * K + cg8 + kbeg;
  const size_t rstep = (size_t)32 * K;

  const int Kt = K >> 6;
  const int nt64 = (blockIdx.y << 1) + (wave >> 1);
  const unsigned short* gBw = Bf + (size_t)(nt64 * Kt + (kbeg >> 6)) * 4096 + lane * 8;

  const int nit = (kend - kbeg) >> 6;              // always even here

  auto issueA = [&](int it) {
    unsigned short* lA = As + (it & 1) * 8192 + tid * 8;
    const unsigned short* g = gA + ((size_t)it << 6);
    cp16(g, lA);
    cp16(g + rstep,     lA + 2048);
    cp16(g + 2 * rstep, lA + 4096);
    cp16(g + 3 * rstep, lA + 6144);
  };
  auto loadB = [&](int it, bf16x8 (&dst)[2][4]) {
    const unsigned short* bt = gBw + (size_t)it * 4096;
    #pragma unroll
    for (int ks = 0; ks < 2; ks++)
      #pragma unroll
      for (int j = 0; j < 4; j++)
        dst[ks][j] = *(const bf16x8*)(bt + (ks * 4 + j) * 512);
  };

  const f32x4 fzero = {0.f, 0.f, 0.f, 0.f};
  f32x4 acc[4][4];
  #pragma unroll
  for (int i = 0; i < 4; i++)
    #pragma unroll
    for (int j = 0; j < 4; j++) acc[i][j] = fzero;

  bf16x8 bcur[2][4], bnext[2][4];

  issueA(0);
  loadB(0, bcur);
  if (nit > 1) issueA(1);

  auto body = [&](int it, bf16x8 (&bc)[2][4], bf16x8 (&bn)[2][4]) {
    if (it + 1 < nit) asm volatile("s_waitcnt vmcnt(12)" ::: "memory");
    else              asm volatile("s_waitcnt vmcnt(8)"  ::: "memory");
    asm volatile("s_barrier" ::: "memory");
    if (it + 1 < nit) loadB(it + 1, bn);

    const unsigned short* cA = As + (it & 1) * 8192;
    #pragma unroll
    for (int ks = 0; ks < 2; ks++) {
      const int sw = (((ks << 2) + q) ^ (c & 7)) << 3;
      bf16x8 af[4];
      #pragma unroll
      for (int i = 0; i < 4; i++) af[i] = *(const bf16x8*)&cA[(wm + i*16 + c)*64 + sw];
      #pragma unroll
      for (int i = 0; i < 4; i++)
        #pragma unroll
        for (int j = 0; j < 4; j++)
          acc[i][j] = __builtin_amdgcn_mfma_f32_16x16x32_bf16(af[i], bc[ks][j], acc[i][j], 0, 0, 0);
    }

    asm volatile("s_barrier" ::: "memory");
    if (it + 2 < nit) issueA(it + 2);
  };

  for (int it = 0; it < nit; it += 2) {
    body(it,     bcur, bnext);
    body(it + 1, bnext, bcur);
  }

  if (MODE == 4) {
    float* op = (float*)outp;
    #pragma unroll
    for (int i = 0; i < 4; i++) {
      #pragma unroll
      for (int r = 0; r < 4; r++) {
        const int row = m0 + wm + i * 16 + q * 4 + r;
        #pragma unroll
        for (int j = 0; j < 4; j++) {
          const int col = n0 + wn + j * 16 + c;
          atomicAdd(op + (size_t)row * N + col, acc[i][j][r]);
        }
      }
    }
  } else {
    float bj[4];
    #pragma unroll
    for (int j = 0; j < 4; j++) bj[j] = bias[n0 + wn + j * 16 + c];
    #pragma unroll
    for (int i = 0; i < 4; i++) {
      #pragma unroll
      for (int r = 0; r < 4; r++) {
        const int row = m0 + wm + i * 16 + q * 4 + r;
        #pragma unroll
        for (int j = 0; j < 4; j++) {
          const int col = n0 + wn + j * 16 + c;
          const size_t idx = (size_t)row * N + col;
          float v = acc[i][j][r] + bj[j];
          if (MODE == 0) ((unsigned short*)outp)[idx] = f2bf(v);
          else           ((unsigned short*)outp)[idx] = f2bf(fmaxf(v, 0.f));
        }
      }
    }
  }
}

template <int MODE>
__global__ __launch_bounds__(256, 3) void gemm_f(
    const unsigned short* __restrict__ A,
    const unsigned short* __restrict__ Bf,
    const float* __restrict__ bias,
    void* __restrict__ outp,
    int N, int K) {
  __shared__ __align__(16) unsigned short As[2 * 8192];
  gemm_core<MODE>(A, Bf, bias, outp, N, K, 0, K, As);
}

__global__ __launch_bounds__(256, 3) void gemm_f_splitk(
    const unsigned short* __restrict__ A,
    const unsigned short* __restrict__ Bf,
    float* __restrict__ outp,
    int N, int K, int CH) {
  __shared__ __align__(16) unsigned short As[2 * 8192];
  const int kbeg = blockIdx.z * CH;
  int kend = kbeg + CH; if (kend > K) kend = K;
  gemm_core<4>(A, Bf, nullptr, outp, N, K, kbeg, kend, As);
}

// ---------------------------------------------------------------------------
// Flash attention, causal + rel_pos bias (round-5 proven version).
// ---------------------------------------------------------------------------
__global__ __launch_bounds__(256, 2) void attn_flash(
    const unsigned short* __restrict__ qkv,   // [4096, 3072] bf16 (q|k|v)
    const float* __restrict__ rel_pos,        // [16, 2048] fp32
    unsigned short* __restrict__ o) {         // [4096, 1024] bf16 ([b,s,h,d])
  __shared__ __align__(16) unsigned short Qs[128 * 64];
  __shared__ __align__(16) unsigned short Ks[64 * 64];
  __shared__ __align__(16) unsigned short Vs[64 * 64];   // transposed [d][kt]
  __shared__ __align__(16) unsigned short Ps[4][32 * 64];
  __shared__ float rps[1024];                            // rel_pos[h,:]*log2e

  const int tid = threadIdx.x;
  const int wave = tid >> 6, lane = tid & 63;
  const int q = lane >> 4, c = lane & 15;

  const int lid = blockIdx.x + (blockIdx.y << 3);
  const int xq = lid & 7, y = lid >> 3;
  const int qt = (y & 32) ? (7 - xq) : xq;
  const int b = y >> 4, h = y & 15;

  const unsigned short* qg = qkv + (size_t)b * 1024 * 3072 + h * 64;
  const unsigned short* kg = qg + 1024;
  const unsigned short* vg = qg + 2048;

  #pragma unroll
  for (int i = 0; i < 4; i++) {
    const int idx = tid + i * 256;
    rps[idx & 1023] = rel_pos[h * 2048 + (idx & 1023)] * 1.44269504f;
  }

  const int sr  = tid >> 3;
  const int cg8 = ((tid & 7) ^ (sr & 7)) << 3;
  #pragma unroll
  for (int it = 0; it < 4; it++)
    cp16(qg + (size_t)(qt * 128 + sr + it * 32) * 3072 + cg8, &Qs[(tid + it * 256) * 8]);
  __syncthreads();

  bf16x8 qf[2][2];
  #pragma unroll
  for (int mt = 0; mt < 2; mt++)
    #pragma unroll
    for (int ks = 0; ks < 2; ks++)
      qf[mt][ks] = *(const bf16x8*)&Qs[(wave*32 + mt*16 + c)*64 + ((((ks<<2)+q) ^ (c & 7)) << 3)];

  const f32x4 fzero = {0.f, 0.f, 0.f, 0.f};
  f32x4 O[2][4];
  float l_i[2][4];
  #pragma unroll
  for (int mt = 0; mt < 2; mt++) {
    #pragma unroll
    for (int r = 0; r < 4; r++) l_i[mt][r] = 0.f;
    #pragma unroll
    for (int dt = 0; dt < 4; dt++) O[mt][dt] = fzero;
  }

  unsigned short* Pw = &Ps[wave][0];
  const int i_base = qt * 128 + wave * 32;
  const int vrow = tid & 63, d0 = (tid >> 6) << 4;
  const int vchunk = vrow >> 3, vlo = vrow & 7;

  const float sc = 0.125f * 1.44269504f;
  const int kdiag = qt << 1;
  const int nkt = (qt + 1) * 2;

  for (int kt = 0; kt < nkt; kt++) {
    __syncthreads();
    cp16(kg + (size_t)(kt * 64 + sr) * 3072 + cg8, &Ks[tid * 8]);
    cp16(kg + (size_t)(kt * 64 + sr + 32) * 3072 + cg8, &Ks[(tid + 256) * 8]);
    {
      union { int4 v; unsigned short u[8]; } va, vb2;
      const unsigned short* vrp = vg + (size_t)(kt * 64 + vrow) * 3072 + d0;
      va.v  = *(const int4*)vrp;
      vb2.v = *(const int4*)(vrp + 8);
      #pragma unroll
      for (int j = 0; j < 8; j++) {
        const int pos = ((vchunk ^ j) << 3) + vlo;
        Vs[(d0 + j) * 64 + pos]     = va.u[j];
        Vs[(d0 + 8 + j) * 64 + pos] = vb2.u[j];
      }
    }
    __syncthreads();

    f32x4 S[2][4];
    #pragma unroll
    for (int mt = 0; mt < 2; mt++)
      #pragma unroll
      for (int nt = 0; nt < 4; nt++) S[mt][nt] = fzero;
    #pragma unroll
    for (int ks = 0; ks < 2; ks++) {
      const int sw = (((ks << 2) + q) ^ (c & 7)) << 3;
      bf16x8 kb[4];
      #pragma unroll
      for (int nt = 0; nt < 4; nt++) kb[nt] = *(const bf16x8*)&Ks[(nt*16 + c)*64 + sw];
      #pragma unroll
      for (int mt = 0; mt < 2; mt++)
        #pragma unroll
        for (int nt = 0; nt < 4; nt++)
          S[mt][nt] = __builtin_amdgcn_mfma_f32_16x16x32_bf16(qf[mt][ks], kb[nt], S[mt][nt], 0, 0, 0);
    }

    if (kt < kdiag) {
      #pragma unroll
      for (int mt = 0; mt < 2; mt++) {
        #pragma unroll
        for (int r = 0; r < 4; r++) {
          const int i_ = i_base + mt * 16 + q * 4 + r;
          const int prow = (mt * 16 + q * 4 + r) * 64;
          const int rsw  = (q * 4 + r) & 7;
          float s = 0.f;
          #pragma unroll
          for (int nt = 0; nt < 4; nt++) {
            const int j_ = kt * 64 + nt * 16 + c;
            const float p = exp2f(fmaf(S[mt][nt][r], sc, rps[i_ - j_]));
            s += p;
            Pw[prow + ((((nt << 1) + (c >> 3)) ^ rsw) << 3) + (c & 7)] = f2bf_fast(p);
          }
          l_i[mt][r] += s;
        }
      }
    } else {
      #pragma unroll
      for (int mt = 0; mt < 2; mt++) {
        #pragma unroll
        for (int r = 0; r < 4; r++) {
          const int i_ = i_base + mt * 16 + q * 4 + r;
          const int prow = (mt * 16 + q * 4 + r) * 64;
          const int rsw  = (q * 4 + r) & 7;
          float s = 0.f;
          #pragma unroll
          for (int nt = 0; nt < 4; nt++) {
            const int j_ = kt * 64 + nt * 16 + c;
            const int d_ = i_ - j_;
            const float p = (d_ >= 0)
                ? exp2f(fmaf(S[mt][nt][r], sc, rps[d_ & 1023])) : 0.f;
            s += p;
            Pw[prow + ((((nt << 1) + (c >> 3)) ^ rsw) << 3) + (c & 7)] = f2bf_fast(p);
          }
          l_i[mt][r] += s;
        }
      }
    }

    asm volatile("s_waitcnt lgkmcnt(0)" ::: "memory");

    #pragma unroll
    for (int ks = 0; ks < 2; ks++) {
      const int sw = (((ks << 2) + q) ^ (c & 7)) << 3;
      bf16x8 pa[2], vb[4];
      #pragma unroll
      for (int mt = 0; mt < 2; mt++) pa[mt] = *(const bf16x8*)&Pw[(mt*16 + c)*64 + sw];
      #pragma unroll
      for (int dt = 0; dt < 4; dt++) vb[dt] = *(const bf16x8*)&Vs[(dt*16 + c)*64 + sw];
      #pragma unroll
      for (int mt = 0; mt < 2; mt++)
        #pragma unroll
        for (int dt = 0; dt < 4; dt++)
          O[mt][dt] = __builtin_amdgcn_mfma_f32_16x16x32_bf16(pa[mt], vb[dt], O[mt][dt], 0, 0, 0);
    }
  }

  #pragma unroll
  for (int mt = 0; mt < 2; mt++) {
    #pragma unroll
    for (int r = 0; r < 4; r++) {
      float l = l_i[mt][r];
      l += __shfl_xor(l, 1, 64);
      l += __shfl_xor(l, 2, 64);
      l += __shfl_xor(l, 4, 64);
      l += __shfl_xor(l, 8, 64);
      const float inv = 1.0f / l;
      const int i_ = i_base + mt * 16 + q * 4 + r;
      unsigned short* orow = o + (size_t)(b * 1024 + i_) * 1024 + h * 64 + c;
      #pragma unroll
      for (int dt = 0; dt < 4; dt++) orow[dt * 16] = f2bf(O[mt][dt][r] * inv);
    }
  }
}

// ---------------------------------------------------------------------------
// Launch
// ---------------------------------------------------------------------------
extern "C" void kernel_launch(void* const* d_in, const int* in_sizes, int n_in,
                              void* d_out, int out_size, void* d_ws, size_t ws_size,
                              hipStream_t stream) {
  (void)in_sizes; (void)n_in; (void)out_size; (void)ws_size;
  const float* x    = (const float*)d_in[0];
  const float* rel  = (const float*)d_in[1];
  const float* ipw  = (const float*)d_in[2];
  const float* ipb  = (const float*)d_in[3];
  const float* outw = (const float*)d_in[4];
  const float* outb = (const float*)d_in[5];
  const float* w1   = (const float*)d_in[6];
  const float* b1   = (const float*)d_in[7];
  const float* w2   = (const float*)d_in[8];
  const float* b2   = (const float*)d_in[9];
  const float* ln1g = (const float*)d_in[10];
  const float* ln1b = (const float*)d_in[11];
  const float* ln2g = (const float*)d_in[12];
  const float* ln2b = (const float*)d_in[13];

  // workspace layout (elements) — frag-major weight buffers, same sizes
  unsigned short* f_ipw  = (unsigned short*)d_ws;            // 3072*1024
  unsigned short* f_outw = f_ipw  + (size_t)3072 * 1024;     // 1024*1024
  unsigned short* f_w1   = f_outw + (size_t)1024 * 1024;     // 4096*1024
  unsigned short* f_w2   = f_w1   + (size_t)4096 * 1024;     // 1024*4096
  unsigned short* xn     = f_w2   + (size_t)1024 * 4096;     // 4096*1024
  unsigned short* qkvb   = xn     + (size_t)4096 * 1024;     // 4096*3072
  unsigned short* ob     = qkvb   + (size_t)4096 * 3072;     // 4096*1024
  float*          x2     = (float*)(ob + (size_t)4096 * 1024);          // 4096*1024 f32
  unsigned short* xm     = (unsigned short*)(x2 + (size_t)4096 * 1024); // 4096*1024
  unsigned short* hb     = xm + (size_t)4096 * 1024;         // 4096*4096

  // all weights -> frag-major bf16, one launch (768+256+1024+1024 tiles)
  cvt_frag<<<3072, 256, 0, stream>>>(ipw, outw, w1, w2, f_ipw, f_outw, f_w1, f_w2);

  // ln1 + seed x2 = x + outb
  ln_bf16_seed<<<4096, 256, 0, stream>>>(x, ln1g, ln1b, xn, outb, x2);

  // QKV proj: grid 768 = 3/CU exact
  gemm_f<0><<<dim3(32, 24), 256, 0, stream>>>(xn, f_ipw, ipb, qkvb, 3072, 1024);

  attn_flash<<<dim3(8, 64), 256, 0, stream>>>(qkvb, rel, ob);

  // attn out proj: x2 += ob @ outw^T  (split-K=3, chunks 384/384/256, 768 blocks)
  gemm_f_splitk<<<dim3(32, 8, 3), 256, 0, stream>>>(ob, f_outw, x2, 1024, 1024, 384);

  // ln2 + seed d_out = x2 + b2
  ln_bf16_seed<<<4096, 256, 0, stream>>>(x2, ln2g, ln2b, xm, b2, (float*)d_out);

  // MLP up
  gemm_f<2><<<dim3(32, 32), 256, 0, stream>>>(xm, f_w1, b1, hb, 4096, 1024);

  // MLP down: d_out += hb @ w2^T  (split-K=3, chunks 1408/1408/1280, 768 blocks)
  gemm_f_splitk<<<dim3(32, 8, 3), 256, 0, stream>>>(hb, f_w2, (float*)d_out, 1024, 4096, 1408);
}

// Round 8
// 348.233 us; speedup vs baseline: 1.1657x; 1.1657x over previous
//
#include <hip/hip_runtime.h>
#include <stdint.h>

// ---------------------------------------------------------------------------
// Types / helpers
// ---------------------------------------------------------------------------
typedef __bf16 bf16x8 __attribute__((ext_vector_type(8)));
typedef float  f32x4  __attribute__((ext_vector_type(4)));

__device__ __forceinline__ unsigned short f2bf(float f) {
  union { float f; unsigned int u; } a; a.f = f;
  unsigned int r = a.u + 0x7FFFu + ((a.u >> 16) & 1u);   // RNE
  return (unsigned short)(r >> 16);
}

__device__ __forceinline__ unsigned short f2bf_fast(float f) {
  union { __bf16 b; unsigned short u; } v; v.b = (__bf16)f; return v.u;
}

// async global->LDS, 16B per lane. LDS dest must be wave-uniform base + lane*16.
__device__ __forceinline__ void cp16(const void* g, void* l) {
  auto g1 = reinterpret_cast<__attribute__((address_space(1))) unsigned int*>(
      reinterpret_cast<uintptr_t>(g));
  auto l3 = reinterpret_cast<__attribute__((address_space(3))) unsigned int*>(
      reinterpret_cast<uintptr_t>(l));
  __builtin_amdgcn_global_load_lds(g1, l3, 16, 0, 0);
}

// ---------------------------------------------------------------------------
// Fused: weight fp32->bf16 convert (blocks 0..12287) AND ln1+seed (blocks
// 12288..16383). Independent work, one launch to cut a kernel gap.
// ---------------------------------------------------------------------------
__global__ __launch_bounds__(256) void cvt_ln1(
    const float* __restrict__ s0, const float* __restrict__ s1,
    const float* __restrict__ s2, const float* __restrict__ s3,
    unsigned short* __restrict__ d0, unsigned short* __restrict__ d1,
    unsigned short* __restrict__ d2, unsigned short* __restrict__ d3,
    const float* __restrict__ x,
    const float* __restrict__ g,
    const float* __restrict__ bta,
    unsigned short* __restrict__ out,
    const float* __restrict__ seed_bias,
    float* __restrict__ seed_out) {
  if (blockIdx.x < 12288) {
    int i = (blockIdx.x * 256 + threadIdx.x) * 4;
    const float* src; unsigned short* dst; int off;
    if (i < 3145728)       { src = s0; dst = d0; off = 0; }
    else if (i < 4194304)  { src = s1; dst = d1; off = 3145728; }
    else if (i < 8388608)  { src = s2; dst = d2; off = 4194304; }
    else                   { src = s3; dst = d3; off = 8388608; }
    i -= off;
    float4 v = *(const float4*)(src + i);
    union { unsigned short u[4]; uint2 p; } o;
    o.u[0] = f2bf(v.x); o.u[1] = f2bf(v.y); o.u[2] = f2bf(v.z); o.u[3] = f2bf(v.w);
    *(uint2*)(dst + i) = o.p;
    return;
  }
  const int row = blockIdx.x - 12288, t = threadIdx.x;
  const float4 v = *(const float4*)(x + (size_t)row * 1024 + t * 4);
  {
    float4 sb = *(const float4*)(seed_bias + t * 4);
    float4 sv;
    sv.x = v.x + sb.x; sv.y = v.y + sb.y; sv.z = v.z + sb.z; sv.w = v.w + sb.w;
    *(float4*)(seed_out + (size_t)row * 1024 + t * 4) = sv;
  }
  float s1v = v.x + v.y + v.z + v.w;
  float s2v = v.x*v.x + v.y*v.y + v.z*v.z + v.w*v.w;
  #pragma unroll
  for (int off = 1; off < 64; off <<= 1) {
    s1v += __shfl_xor(s1v, off, 64);
    s2v += __shfl_xor(s2v, off, 64);
  }
  __shared__ float r1[4], r2[4];
  if ((t & 63) == 0) { r1[t >> 6] = s1v; r2[t >> 6] = s2v; }
  __syncthreads();
  s1v = r1[0] + r1[1] + r1[2] + r1[3];
  s2v = r2[0] + r2[1] + r2[2] + r2[3];
  const float mean = s1v * (1.0f / 1024.0f);
  const float var  = s2v * (1.0f / 1024.0f) - mean * mean;
  const float rstd = rsqrtf(var + 1e-5f);
  const float4 gv = *(const float4*)(g + t * 4);
  const float4 bv = *(const float4*)(bta + t * 4);
  union { unsigned short u[4]; uint2 p; } o;
  o.u[0] = f2bf((v.x - mean) * rstd * gv.x + bv.x);
  o.u[1] = f2bf((v.y - mean) * rstd * gv.y + bv.y);
  o.u[2] = f2bf((v.z - mean) * rstd * gv.z + bv.z);
  o.u[3] = f2bf((v.w - mean) * rstd * gv.w + bv.w);
  *(uint2*)(out + (size_t)row * 1024 + t * 4) = o.p;
}

// ---------------------------------------------------------------------------
// LayerNorm (E=1024), fp32 in -> bf16 out, PLUS seeds the next split-K GEMM's
// accumulator: seed_out[row,:] = x[row,:] + seed_bias[:].
// ---------------------------------------------------------------------------
__global__ __launch_bounds__(256) void ln_bf16_seed(
    const float* __restrict__ x,
    const float* __restrict__ g,
    const float* __restrict__ bta,
    unsigned short* __restrict__ out,
    const float* __restrict__ seed_bias,
    float* __restrict__ seed_out) {
  const int row = blockIdx.x, t = threadIdx.x;
  const float4 v = *(const float4*)(x + (size_t)row * 1024 + t * 4);
  {
    float4 sb = *(const float4*)(seed_bias + t * 4);
    float4 sv;
    sv.x = v.x + sb.x; sv.y = v.y + sb.y; sv.z = v.z + sb.z; sv.w = v.w + sb.w;
    *(float4*)(seed_out + (size_t)row * 1024 + t * 4) = sv;
  }
  float s1 = v.x + v.y + v.z + v.w;
  float s2 = v.x*v.x + v.y*v.y + v.z*v.z + v.w*v.w;
  #pragma unroll
  for (int off = 1; off < 64; off <<= 1) {
    s1 += __shfl_xor(s1, off, 64);
    s2 += __shfl_xor(s2, off, 64);
  }
  __shared__ float r1[4], r2[4];
  if ((t & 63) == 0) { r1[t >> 6] = s1; r2[t >> 6] = s2; }
  __syncthreads();
  s1 = r1[0] + r1[1] + r1[2] + r1[3];
  s2 = r2[0] + r2[1] + r2[2] + r2[3];
  const float mean = s1 * (1.0f / 1024.0f);
  const float var  = s2 * (1.0f / 1024.0f) - mean * mean;
  const float rstd = rsqrtf(var + 1e-5f);
  const float4 gv = *(const float4*)(g + t * 4);
  const float4 bv = *(const float4*)(bta + t * 4);
  union { unsigned short u[4]; uint2 p; } o;
  o.u[0] = f2bf((v.x - mean) * rstd * gv.x + bv.x);
  o.u[1] = f2bf((v.y - mean) * rstd * gv.y + bv.y);
  o.u[2] = f2bf((v.z - mean) * rstd * gv.z + bv.z);
  o.u[3] = f2bf((v.w - mean) * rstd * gv.w + bv.w);
  *(uint2*)(out + (size_t)row * 1024 + t * 4) = o.p;
}

// ---------------------------------------------------------------------------
// Pipelined GEMM core (R5 mechanics, 48 KB LDS -> 3 blocks/CU):
// A double-buffered (2 x 16 KB), B single-buffered (16 KB), BK=64.
// Steady state: wait vmcnt(4) (A(it)+B(it) drained, A(it+1) in flight),
// raw s_barrier, 16 MFMA/wave, s_barrier, issue B(it+1) + A(it+2).
// LDS chunk-XOR swizzle -> ds_read_b128 bank aliasing is 2-way (free).
// MODE 0 = bf16 v+bias; MODE 2 = bf16 relu(v+bias); MODE 4 = atomic fp32 +=v.
// ---------------------------------------------------------------------------
template <int MODE>
__device__ __forceinline__ void gemm_core(
    const unsigned short* __restrict__ A,
    const unsigned short* __restrict__ Bt,
    const float* __restrict__ bias,
    void* __restrict__ outp,
    int N, int K, int kbeg, int kend,
    unsigned short* As,    // 2 * 8192 elems
    unsigned short* Bs) {  // 8192 elems
  const int tid = threadIdx.x;
  const int wave = tid >> 6, lane = tid & 63;
  const int q = lane >> 4, c = lane & 15;
  const int wm = (wave & 1) << 6, wn = (wave >> 1) << 6;
  const int m0 = blockIdx.x << 7, n0 = blockIdx.y << 7;

  const int srow = tid >> 3;                       // 0..31
  const int cg8  = ((tid & 7) ^ (srow & 7)) << 3;  // swizzled col chunk

  const unsigned short* gA = A  + (size_t)(m0 + srow) * K + cg8 + kbeg;
  const unsigned short* gB = Bt + (size_t)(n0 + srow) * K + cg8 + kbeg;
  const size_t rstep = (size_t)32 * K;

  const int nit = (kend - kbeg) >> 6;

  auto issueA = [&](int it) {
    unsigned short* lA = As + (it & 1) * 8192 + tid * 8;
    const unsigned short* g = gA + ((size_t)it << 6);
    cp16(g,             lA);
    cp16(g + rstep,     lA + 2048);
    cp16(g + 2 * rstep, lA + 4096);
    cp16(g + 3 * rstep, lA + 6144);
  };
  auto issueB = [&](int it) {
    unsigned short* lB = Bs + tid * 8;
    const unsigned short* g = gB + ((size_t)it << 6);
    cp16(g,             lB);
    cp16(g + rstep,     lB + 2048);
    cp16(g + 2 * rstep, lB + 4096);
    cp16(g + 3 * rstep, lB + 6144);
  };

  const f32x4 fzero = {0.f, 0.f, 0.f, 0.f};
  f32x4 acc[4][4];
  #pragma unroll
  for (int i = 0; i < 4; i++)
    #pragma unroll
    for (int j = 0; j < 4; j++) acc[i][j] = fzero;

  // prologue: A0, B0, A1  (issue order matters for vmcnt accounting)
  issueA(0);
  issueB(0);
  if (nit > 1) issueA(1);

  for (int it = 0; it < nit; ++it) {
    // drain A(it)+B(it); A(it+1) (4 ops) stays in flight
    if (it + 1 < nit) asm volatile("s_waitcnt vmcnt(4)" ::: "memory");
    else              asm volatile("s_waitcnt vmcnt(0)" ::: "memory");
    asm volatile("s_barrier" ::: "memory");

    const unsigned short* cA = As + (it & 1) * 8192;
    #pragma unroll
    for (int ks = 0; ks < 2; ks++) {
      const int sw = (((ks << 2) + q) ^ (c & 7)) << 3;
      bf16x8 af[4], bf[4];
      #pragma unroll
      for (int i = 0; i < 4; i++) af[i] = *(const bf16x8*)&cA[(wm + i*16 + c)*64 + sw];
      #pragma unroll
      for (int j = 0; j < 4; j++) bf[j] = *(const bf16x8*)&Bs[(wn + j*16 + c)*64 + sw];
      #pragma unroll
      for (int i = 0; i < 4; i++)
        #pragma unroll
        for (int j = 0; j < 4; j++)
          acc[i][j] = __builtin_amdgcn_mfma_f32_16x16x32_bf16(af[i], bf[j], acc[i][j], 0, 0, 0);
    }

    // all waves done reading Bs / As[it&1] before refill
    asm volatile("s_barrier" ::: "memory");
    if (it + 1 < nit) issueB(it + 1);
    if (it + 2 < nit) issueA(it + 2);
  }

  if (MODE == 4) {
    float* op = (float*)outp;
    #pragma unroll
    for (int i = 0; i < 4; i++) {
      #pragma unroll
      for (int r = 0; r < 4; r++) {
        const int row = m0 + wm + i * 16 + q * 4 + r;
        #pragma unroll
        for (int j = 0; j < 4; j++) {
          const int col = n0 + wn + j * 16 + c;
          atomicAdd(op + (size_t)row * N + col, acc[i][j][r]);
        }
      }
    }
  } else {
    float bj[4];
    #pragma unroll
    for (int j = 0; j < 4; j++) bj[j] = bias[n0 + wn + j * 16 + c];
    #pragma unroll
    for (int i = 0; i < 4; i++) {
      #pragma unroll
      for (int r = 0; r < 4; r++) {
        const int row = m0 + wm + i * 16 + q * 4 + r;
        #pragma unroll
        for (int j = 0; j < 4; j++) {
          const int col = n0 + wn + j * 16 + c;
          const size_t idx = (size_t)row * N + col;
          float v = acc[i][j][r] + bj[j];
          if (MODE == 0) ((unsigned short*)outp)[idx] = f2bf(v);
          else           ((unsigned short*)outp)[idx] = f2bf(fmaxf(v, 0.f));
        }
      }
    }
  }
}

template <int MODE>
__global__ __launch_bounds__(256, 3) void gemm_s(
    const unsigned short* __restrict__ A,
    const unsigned short* __restrict__ Bt,
    const float* __restrict__ bias,
    void* __restrict__ outp,
    int N, int K) {
  __shared__ __align__(16) unsigned short As[2 * 8192];
  __shared__ __align__(16) unsigned short Bs[8192];
  gemm_core<MODE>(A, Bt, bias, outp, N, K, 0, K, As, Bs);
}

__global__ __launch_bounds__(256, 3) void gemm_s_splitk(
    const unsigned short* __restrict__ A,
    const unsigned short* __restrict__ Bt,
    float* __restrict__ outp,
    int N, int K, int CH) {
  __shared__ __align__(16) unsigned short As[2 * 8192];
  __shared__ __align__(16) unsigned short Bs[8192];
  const int kbeg = blockIdx.z * CH;
  int kend = kbeg + CH; if (kend > K) kend = K;
  gemm_core<4>(A, Bt, nullptr, outp, N, K, kbeg, kend, As, Bs);
}

// ---------------------------------------------------------------------------
// Flash attention, causal + rel_pos bias (round-5 proven version, verbatim).
// ---------------------------------------------------------------------------
__global__ __launch_bounds__(256, 2) void attn_flash(
    const unsigned short* __restrict__ qkv,   // [4096, 3072] bf16 (q|k|v)
    const float* __restrict__ rel_pos,        // [16, 2048] fp32
    unsigned short* __restrict__ o) {         // [4096, 1024] bf16 ([b,s,h,d])
  __shared__ __align__(16) unsigned short Qs[128 * 64];
  __shared__ __align__(16) unsigned short Ks[64 * 64];
  __shared__ __align__(16) unsigned short Vs[64 * 64];   // transposed [d][kt]
  __shared__ __align__(16) unsigned short Ps[4][32 * 64];
  __shared__ float rps[1024];                            // rel_pos[h,:]*log2e

  const int tid = threadIdx.x;
  const int wave = tid >> 6, lane = tid & 63;
  const int q = lane >> 4, c = lane & 15;

  const int lid = blockIdx.x + (blockIdx.y << 3);
  const int xq = lid & 7, y = lid >> 3;
  const int qt = (y & 32) ? (7 - xq) : xq;
  const int b = y >> 4, h = y & 15;

  const unsigned short* qg = qkv + (size_t)b * 1024 * 3072 + h * 64;
  const unsigned short* kg = qg + 1024;
  const unsigned short* vg = qg + 2048;

  #pragma unroll
  for (int i = 0; i < 4; i++) {
    const int idx = tid + i * 256;
    rps[idx & 1023] = rel_pos[h * 2048 + (idx & 1023)] * 1.44269504f;
  }

  const int sr  = tid >> 3;
  const int cg8 = ((tid & 7) ^ (sr & 7)) << 3;
  #pragma unroll
  for (int it = 0; it < 4; it++)
    cp16(qg + (size_t)(qt * 128 + sr + it * 32) * 3072 + cg8, &Qs[(tid + it * 256) * 8]);
  __syncthreads();

  bf16x8 qf[2][2];
  #pragma unroll
  for (int mt = 0; mt < 2; mt++)
    #pragma unroll
    for (int ks = 0; ks < 2; ks++)
      qf[mt][ks] = *(const bf16x8*)&Qs[(wave*32 + mt*16 + c)*64 + ((((ks<<2)+q) ^ (c & 7)) << 3)];

  const f32x4 fzero = {0.f, 0.f, 0.f, 0.f};
  f32x4 O[2][4];
  float l_i[2][4];
  #pragma unroll
  for (int mt = 0; mt < 2; mt++) {
    #pragma unroll
    for (int r = 0; r < 4; r++) l_i[mt][r] = 0.f;
    #pragma unroll
    for (int dt = 0; dt < 4; dt++) O[mt][dt] = fzero;
  }

  unsigned short* Pw = &Ps[wave][0];
  const int i_base = qt * 128 + wave * 32;
  const int vrow = tid & 63, d0 = (tid >> 6) << 4;
  const int vchunk = vrow >> 3, vlo = vrow & 7;

  const float sc = 0.125f * 1.44269504f;
  const int kdiag = qt << 1;
  const int nkt = (qt + 1) * 2;

  for (int kt = 0; kt < nkt; kt++) {
    __syncthreads();
    cp16(kg + (size_t)(kt * 64 + sr) * 3072 + cg8, &Ks[tid * 8]);
    cp16(kg + (size_t)(kt * 64 + sr + 32) * 3072 + cg8, &Ks[(tid + 256) * 8]);
    {
      union { int4 v; unsigned short u[8]; } va, vb2;
      const unsigned short* vrp = vg + (size_t)(kt * 64 + vrow) * 3072 + d0;
      va.v  = *(const int4*)vrp;
      vb2.v = *(const int4*)(vrp + 8);
      #pragma unroll
      for (int j = 0; j < 8; j++) {
        const int pos = ((vchunk ^ j) << 3) + vlo;
        Vs[(d0 + j) * 64 + pos]     = va.u[j];
        Vs[(d0 + 8 + j) * 64 + pos] = vb2.u[j];
      }
    }
    __syncthreads();

    f32x4 S[2][4];
    #pragma unroll
    for (int mt = 0; mt < 2; mt++)
      #pragma unroll
      for (int nt = 0; nt < 4; nt++) S[mt][nt] = fzero;
    #pragma unroll
    for (int ks = 0; ks < 2; ks++) {
      const int sw = (((ks << 2) + q) ^ (c & 7)) << 3;
      bf16x8 kb[4];
      #pragma unroll
      for (int nt = 0; nt < 4; nt++) kb[nt] = *(const bf16x8*)&Ks[(nt*16 + c)*64 + sw];
      #pragma unroll
      for (int mt = 0; mt < 2; mt++)
        #pragma unroll
        for (int nt = 0; nt < 4; nt++)
          S[mt][nt] = __builtin_amdgcn_mfma_f32_16x16x32_bf16(qf[mt][ks], kb[nt], S[mt][nt], 0, 0, 0);
    }

    if (kt < kdiag) {
      #pragma unroll
      for (int mt = 0; mt < 2; mt++) {
        #pragma unroll
        for (int r = 0; r < 4; r++) {
          const int i_ = i_base + mt * 16 + q * 4 + r;
          const int prow = (mt * 16 + q * 4 + r) * 64;
          const int rsw  = (q * 4 + r) & 7;
          float s = 0.f;
          #pragma unroll
          for (int nt = 0; nt < 4; nt++) {
            const int j_ = kt * 64 + nt * 16 + c;
            const float p = exp2f(fmaf(S[mt][nt][r], sc, rps[i_ - j_]));
            s += p;
            Pw[prow + ((((nt << 1) + (c >> 3)) ^ rsw) << 3) + (c & 7)] = f2bf_fast(p);
          }
          l_i[mt][r] += s;
        }
      }
    } else {
      #pragma unroll
      for (int mt = 0; mt < 2; mt++) {
        #pragma unroll
        for (int r = 0; r < 4; r++) {
          const int i_ = i_base + mt * 16 + q * 4 + r;
          const int prow = (mt * 16 + q * 4 + r) * 64;
          const int rsw  = (q * 4 + r) & 7;
          float s = 0.f;
          #pragma unroll
          for (int nt = 0; nt < 4; nt++) {
            const int j_ = kt * 64 + nt * 16 + c;
            const int d_ = i_ - j_;
            const float p = (d_ >= 0)
                ? exp2f(fmaf(S[mt][nt][r], sc, rps[d_ & 1023])) : 0.f;
            s += p;
            Pw[prow + ((((nt << 1) + (c >> 3)) ^ rsw) << 3) + (c & 7)] = f2bf_fast(p);
          }
          l_i[mt][r] += s;
        }
      }
    }

    asm volatile("s_waitcnt lgkmcnt(0)" ::: "memory");

    #pragma unroll
    for (int ks = 0; ks < 2; ks++) {
      const int sw = (((ks << 2) + q) ^ (c & 7)) << 3;
      bf16x8 pa[2], vb[4];
      #pragma unroll
      for (int mt = 0; mt < 2; mt++) pa[mt] = *(const bf16x8*)&Pw[(mt*16 + c)*64 + sw];
      #pragma unroll
      for (int dt = 0; dt < 4; dt++) vb[dt] = *(const bf16x8*)&Vs[(dt*16 + c)*64 + sw];
      #pragma unroll
      for (int mt = 0; mt < 2; mt++)
        #pragma unroll
        for (int dt = 0; dt < 4; dt++)
          O[mt][dt] = __builtin_amdgcn_mfma_f32_16x16x32_bf16(pa[mt], vb[dt], O[mt][dt], 0, 0, 0);
    }
  }

  #pragma unroll
  for (int mt = 0; mt < 2; mt++) {
    #pragma unroll
    for (int r = 0; r < 4; r++) {
      float l = l_i[mt][r];
      l += __shfl_xor(l, 1, 64);
      l += __shfl_xor(l, 2, 64);
      l += __shfl_xor(l, 4, 64);
      l += __shfl_xor(l, 8, 64);
      const float inv = 1.0f / l;
      const int i_ = i_base + mt * 16 + q * 4 + r;
      unsigned short* orow = o + (size_t)(b * 1024 + i_) * 1024 + h * 64 + c;
      #pragma unroll
      for (int dt = 0; dt < 4; dt++) orow[dt * 16] = f2bf(O[mt][dt][r] * inv);
    }
  }
}

// ---------------------------------------------------------------------------
// Launch
// ---------------------------------------------------------------------------
extern "C" void kernel_launch(void* const* d_in, const int* in_sizes, int n_in,
                              void* d_out, int out_size, void* d_ws, size_t ws_size,
                              hipStream_t stream) {
  (void)in_sizes; (void)n_in; (void)out_size; (void)ws_size;
  const float* x    = (const float*)d_in[0];
  const float* rel  = (const float*)d_in[1];
  const float* ipw  = (const float*)d_in[2];
  const float* ipb  = (const float*)d_in[3];
  const float* outw = (const float*)d_in[4];
  const float* outb = (const float*)d_in[5];
  const float* w1   = (const float*)d_in[6];
  const float* b1   = (const float*)d_in[7];
  const float* w2   = (const float*)d_in[8];
  const float* b2   = (const float*)d_in[9];
  const float* ln1g = (const float*)d_in[10];
  const float* ln1b = (const float*)d_in[11];
  const float* ln2g = (const float*)d_in[12];
  const float* ln2b = (const float*)d_in[13];

  // workspace layout (elements)
  unsigned short* ipw_b  = (unsigned short*)d_ws;            // 3072*1024
  unsigned short* outw_b = ipw_b  + (size_t)3072 * 1024;     // 1024*1024
  unsigned short* w1_b   = outw_b + (size_t)1024 * 1024;     // 4096*1024
  unsigned short* w2_b   = w1_b   + (size_t)4096 * 1024;     // 1024*4096
  unsigned short* xn     = w2_b   + (size_t)1024 * 4096;     // 4096*1024
  unsigned short* qkvb   = xn     + (size_t)4096 * 1024;     // 4096*3072
  unsigned short* ob     = qkvb   + (size_t)4096 * 3072;     // 4096*1024
  float*          x2     = (float*)(ob + (size_t)4096 * 1024);          // 4096*1024 f32
  unsigned short* xm     = (unsigned short*)(x2 + (size_t)4096 * 1024); // 4096*1024
  unsigned short* hb     = xm + (size_t)4096 * 1024;         // 4096*4096

  // fused: weight converts + ln1 + seed x2 = x + outb
  cvt_ln1<<<16384, 256, 0, stream>>>(ipw, outw, w1, w2, ipw_b, outw_b, w1_b, w2_b,
                                     x, ln1g, ln1b, xn, outb, x2);

  // QKV proj: grid 768 = 3/CU exact
  gemm_s<0><<<dim3(32, 24), 256, 0, stream>>>(xn, ipw_b, ipb, qkvb, 3072, 1024);

  attn_flash<<<dim3(8, 64), 256, 0, stream>>>(qkvb, rel, ob);

  // attn out proj: x2 += ob @ outw^T  (split-K=2, atomic)
  gemm_s_splitk<<<dim3(32, 8, 2), 256, 0, stream>>>(ob, outw_b, x2, 1024, 1024, 512);

  // ln2 + seed d_out = x2 + b2
  ln_bf16_seed<<<4096, 256, 0, stream>>>(x2, ln2g, ln2b, xm, b2, (float*)d_out);

  // MLP up
  gemm_s<2><<<dim3(32, 32), 256, 0, stream>>>(xm, w1_b, b1, hb, 4096, 1024);

  // MLP down: d_out += hb @ w2^T  (split-K=3 -> 768 blocks = 3/CU exact)
  gemm_s_splitk<<<dim3(32, 8, 3), 256, 0, stream>>>(hb, w2_b, (float*)d_out, 1024, 4096, 1408);
}

// Round 9
// 328.479 us; speedup vs baseline: 1.2358x; 1.0601x over previous
//
#include <hip/hip_runtime.h>
#include <stdint.h>

// ---------------------------------------------------------------------------
// Types / helpers
// ---------------------------------------------------------------------------
typedef __bf16 bf16x8 __attribute__((ext_vector_type(8)));
typedef float  f32x4  __attribute__((ext_vector_type(4)));

__device__ __forceinline__ unsigned short f2bf(float f) {
  union { float f; unsigned int u; } a; a.f = f;
  unsigned int r = a.u + 0x7FFFu + ((a.u >> 16) & 1u);   // RNE
  return (unsigned short)(r >> 16);
}

__device__ __forceinline__ unsigned short f2bf_fast(float f) {
  union { __bf16 b; unsigned short u; } v; v.b = (__bf16)f; return v.u;
}

// async global->LDS, 16B per lane. LDS dest must be wave-uniform base + lane*16.
__device__ __forceinline__ void cp16(const void* g, void* l) {
  auto g1 = reinterpret_cast<__attribute__((address_space(1))) unsigned int*>(
      reinterpret_cast<uintptr_t>(g));
  auto l3 = reinterpret_cast<__attribute__((address_space(3))) unsigned int*>(
      reinterpret_cast<uintptr_t>(l));
  __builtin_amdgcn_global_load_lds(g1, l3, 16, 0, 0);
}

// ---------------------------------------------------------------------------
// Fused: weight fp32->bf16 convert (blocks 0..12287) AND ln1+seed (blocks
// 12288..16383). Independent work, one launch to cut a kernel gap.
// ---------------------------------------------------------------------------
__global__ __launch_bounds__(256) void cvt_ln1(
    const float* __restrict__ s0, const float* __restrict__ s1,
    const float* __restrict__ s2, const float* __restrict__ s3,
    unsigned short* __restrict__ d0, unsigned short* __restrict__ d1,
    unsigned short* __restrict__ d2, unsigned short* __restrict__ d3,
    const float* __restrict__ x,
    const float* __restrict__ g,
    const float* __restrict__ bta,
    unsigned short* __restrict__ out,
    const float* __restrict__ seed_bias,
    float* __restrict__ seed_out) {
  if (blockIdx.x < 12288) {
    int i = (blockIdx.x * 256 + threadIdx.x) * 4;
    const float* src; unsigned short* dst; int off;
    if (i < 3145728)       { src = s0; dst = d0; off = 0; }
    else if (i < 4194304)  { src = s1; dst = d1; off = 3145728; }
    else if (i < 8388608)  { src = s2; dst = d2; off = 4194304; }
    else                   { src = s3; dst = d3; off = 8388608; }
    i -= off;
    float4 v = *(const float4*)(src + i);
    union { unsigned short u[4]; uint2 p; } o;
    o.u[0] = f2bf(v.x); o.u[1] = f2bf(v.y); o.u[2] = f2bf(v.z); o.u[3] = f2bf(v.w);
    *(uint2*)(dst + i) = o.p;
    return;
  }
  const int row = blockIdx.x - 12288, t = threadIdx.x;
  const float4 v = *(const float4*)(x + (size_t)row * 1024 + t * 4);
  {
    float4 sb = *(const float4*)(seed_bias + t * 4);
    float4 sv;
    sv.x = v.x + sb.x; sv.y = v.y + sb.y; sv.z = v.z + sb.z; sv.w = v.w + sb.w;
    *(float4*)(seed_out + (size_t)row * 1024 + t * 4) = sv;
  }
  float s1v = v.x + v.y + v.z + v.w;
  float s2v = v.x*v.x + v.y*v.y + v.z*v.z + v.w*v.w;
  #pragma unroll
  for (int off = 1; off < 64; off <<= 1) {
    s1v += __shfl_xor(s1v, off, 64);
    s2v += __shfl_xor(s2v, off, 64);
  }
  __shared__ float r1[4], r2[4];
  if ((t & 63) == 0) { r1[t >> 6] = s1v; r2[t >> 6] = s2v; }
  __syncthreads();
  s1v = r1[0] + r1[1] + r1[2] + r1[3];
  s2v = r2[0] + r2[1] + r2[2] + r2[3];
  const float mean = s1v * (1.0f / 1024.0f);
  const float var  = s2v * (1.0f / 1024.0f) - mean * mean;
  const float rstd = rsqrtf(var + 1e-5f);
  const float4 gv = *(const float4*)(g + t * 4);
  const float4 bv = *(const float4*)(bta + t * 4);
  union { unsigned short u[4]; uint2 p; } o;
  o.u[0] = f2bf((v.x - mean) * rstd * gv.x + bv.x);
  o.u[1] = f2bf((v.y - mean) * rstd * gv.y + bv.y);
  o.u[2] = f2bf((v.z - mean) * rstd * gv.z + bv.z);
  o.u[3] = f2bf((v.w - mean) * rstd * gv.w + bv.w);
  *(uint2*)(out + (size_t)row * 1024 + t * 4) = o.p;
}

// ---------------------------------------------------------------------------
// LayerNorm (E=1024), fp32 in -> bf16 out, PLUS seeds the next split-K GEMM's
// accumulator: seed_out[row,:] = x[row,:] + seed_bias[:].
// ---------------------------------------------------------------------------
__global__ __launch_bounds__(256) void ln_bf16_seed(
    const float* __restrict__ x,
    const float* __restrict__ g,
    const float* __restrict__ bta,
    unsigned short* __restrict__ out,
    const float* __restrict__ seed_bias,
    float* __restrict__ seed_out) {
  const int row = blockIdx.x, t = threadIdx.x;
  const float4 v = *(const float4*)(x + (size_t)row * 1024 + t * 4);
  {
    float4 sb = *(const float4*)(seed_bias + t * 4);
    float4 sv;
    sv.x = v.x + sb.x; sv.y = v.y + sb.y; sv.z = v.z + sb.z; sv.w = v.w + sb.w;
    *(float4*)(seed_out + (size_t)row * 1024 + t * 4) = sv;
  }
  float s1 = v.x + v.y + v.z + v.w;
  float s2 = v.x*v.x + v.y*v.y + v.z*v.z + v.w*v.w;
  #pragma unroll
  for (int off = 1; off < 64; off <<= 1) {
    s1 += __shfl_xor(s1, off, 64);
    s2 += __shfl_xor(s2, off, 64);
  }
  __shared__ float r1[4], r2[4];
  if ((t & 63) == 0) { r1[t >> 6] = s1; r2[t >> 6] = s2; }
  __syncthreads();
  s1 = r1[0] + r1[1] + r1[2] + r1[3];
  s2 = r2[0] + r2[1] + r2[2] + r2[3];
  const float mean = s1 * (1.0f / 1024.0f);
  const float var  = s2 * (1.0f / 1024.0f) - mean * mean;
  const float rstd = rsqrtf(var + 1e-5f);
  const float4 gv = *(const float4*)(g + t * 4);
  const float4 bv = *(const float4*)(bta + t * 4);
  union { unsigned short u[4]; uint2 p; } o;
  o.u[0] = f2bf((v.x - mean) * rstd * gv.x + bv.x);
  o.u[1] = f2bf((v.y - mean) * rstd * gv.y + bv.y);
  o.u[2] = f2bf((v.z - mean) * rstd * gv.z + bv.z);
  o.u[3] = f2bf((v.w - mean) * rstd * gv.w + bv.w);
  *(uint2*)(out + (size_t)row * 1024 + t * 4) = o.p;
}

// ---------------------------------------------------------------------------
// Pipelined GEMM core (R5 proven optimum). Double-buffered LDS (2 x 32KB),
// AITER-style K-loop: prefetch batch k+1 stays in flight across the barrier;
// vmcnt(8) steady state, vmcnt(0) only on the last iteration. Raw s_barrier.
// 2 blocks/CU; measured best vs single-buf-B@3/CU (R8) and BK=32 ring (R6).
// MODE 0 = bf16 v+bias; MODE 2 = bf16 relu(v+bias); MODE 4 = atomic fp32 +=v.
// ---------------------------------------------------------------------------
template <int MODE>
__device__ __forceinline__ void gemm_core(
    const unsigned short* __restrict__ A,
    const unsigned short* __restrict__ Bt,
    const float* __restrict__ bias,
    void* __restrict__ outp,
    int N, int K, int kbeg, int kend,
    unsigned short* As, unsigned short* Bs) {   // each [2][128*64]
  const int tid = threadIdx.x;
  const int wave = tid >> 6, lane = tid & 63;
  const int q = lane >> 4, c = lane & 15;
  const int wm = (wave & 1) << 6, wn = (wave >> 1) << 6;
  const int m0 = blockIdx.x << 7, n0 = blockIdx.y << 7;

  const int srow = tid >> 3;                       // 0..31
  const int cg8  = ((tid & 7) ^ (srow & 7)) << 3;  // swizzled col chunk

  const unsigned short* gA = A  + (size_t)(m0 + srow) * K + cg8;
  const unsigned short* gB = Bt + (size_t)(n0 + srow) * K + cg8;
  const size_t rstep = (size_t)32 * K;

  auto issue = [&](int k0, int buf) {
    unsigned short* lA = As + buf * 8192 + tid * 8;
    unsigned short* lB = Bs + buf * 8192 + tid * 8;
    #pragma unroll
    for (int it = 0; it < 4; it++) {
      cp16(gA + it * rstep + k0, lA + it * 2048);
      cp16(gB + it * rstep + k0, lB + it * 2048);
    }
  };

  const f32x4 fzero = {0.f, 0.f, 0.f, 0.f};
  f32x4 acc[4][4];
  #pragma unroll
  for (int i = 0; i < 4; i++)
    #pragma unroll
    for (int j = 0; j < 4; j++) acc[i][j] = fzero;

  issue(kbeg, 0);
  if (kbeg + 64 < kend) issue(kbeg + 64, 1);

  int buf = 0;
  for (int k0 = kbeg; k0 < kend; k0 += 64, buf ^= 1) {
    if (k0 + 64 < kend) asm volatile("s_waitcnt vmcnt(8)" ::: "memory");
    else                asm volatile("s_waitcnt vmcnt(0)" ::: "memory");
    asm volatile("s_barrier" ::: "memory");

    const unsigned short* cA = As + buf * 8192;
    const unsigned short* cB = Bs + buf * 8192;
    #pragma unroll
    for (int ks = 0; ks < 2; ks++) {
      const int sw = (((ks << 2) + q) ^ (c & 7)) << 3;
      bf16x8 af[4], bf[4];
      #pragma unroll
      for (int i = 0; i < 4; i++) af[i] = *(const bf16x8*)&cA[(wm + i*16 + c)*64 + sw];
      #pragma unroll
      for (int j = 0; j < 4; j++) bf[j] = *(const bf16x8*)&cB[(wn + j*16 + c)*64 + sw];
      #pragma unroll
      for (int i = 0; i < 4; i++)
        #pragma unroll
        for (int j = 0; j < 4; j++)
          acc[i][j] = __builtin_amdgcn_mfma_f32_16x16x32_bf16(af[i], bf[j], acc[i][j], 0, 0, 0);
    }

    asm volatile("s_barrier" ::: "memory");
    if (k0 + 128 < kend) issue(k0 + 128, buf);
  }

  if (MODE == 4) {
    float* op = (float*)outp;
    #pragma unroll
    for (int i = 0; i < 4; i++) {
      #pragma unroll
      for (int r = 0; r < 4; r++) {
        const int row = m0 + wm + i * 16 + q * 4 + r;
        #pragma unroll
        for (int j = 0; j < 4; j++) {
          const int col = n0 + wn + j * 16 + c;
          atomicAdd(op + (size_t)row * N + col, acc[i][j][r]);
        }
      }
    }
  } else {
    float bj[4];
    #pragma unroll
    for (int j = 0; j < 4; j++) bj[j] = bias[n0 + wn + j * 16 + c];
    #pragma unroll
    for (int i = 0; i < 4; i++) {
      #pragma unroll
      for (int r = 0; r < 4; r++) {
        const int row = m0 + wm + i * 16 + q * 4 + r;
        #pragma unroll
        for (int j = 0; j < 4; j++) {
          const int col = n0 + wn + j * 16 + c;
          const size_t idx = (size_t)row * N + col;
          float v = acc[i][j][r] + bj[j];
          if (MODE == 0) ((unsigned short*)outp)[idx] = f2bf(v);
          else           ((unsigned short*)outp)[idx] = f2bf(fmaxf(v, 0.f));
        }
      }
    }
  }
}

template <int MODE>
__global__ __launch_bounds__(256, 2) void gemm_bt(
    const unsigned short* __restrict__ A,
    const unsigned short* __restrict__ Bt,
    const float* __restrict__ bias,
    void* __restrict__ outp,
    int N, int K) {
  __shared__ __align__(16) unsigned short As[2 * 8192];
  __shared__ __align__(16) unsigned short Bs[2 * 8192];
  gemm_core<MODE>(A, Bt, bias, outp, N, K, 0, K, As, Bs);
}

// split-K=2: z in {0,1}, atomicAdd into pre-seeded fp32 output
__global__ __launch_bounds__(256, 2) void gemm_bt_splitk(
    const unsigned short* __restrict__ A,
    const unsigned short* __restrict__ Bt,
    float* __restrict__ outp,
    int N, int K) {
  __shared__ __align__(16) unsigned short As[2 * 8192];
  __shared__ __align__(16) unsigned short Bs[2 * 8192];
  const int KH = K >> 1;
  const int kbeg = blockIdx.z * KH;
  gemm_core<4>(A, Bt, nullptr, outp, N, K, kbeg, kbeg + KH, As, Bs);
}

// ---------------------------------------------------------------------------
// Flash attention, causal + rel_pos bias (round-5 proven version, verbatim).
// ---------------------------------------------------------------------------
__global__ __launch_bounds__(256, 2) void attn_flash(
    const unsigned short* __restrict__ qkv,   // [4096, 3072] bf16 (q|k|v)
    const float* __restrict__ rel_pos,        // [16, 2048] fp32
    unsigned short* __restrict__ o) {         // [4096, 1024] bf16 ([b,s,h,d])
  __shared__ __align__(16) unsigned short Qs[128 * 64];
  __shared__ __align__(16) unsigned short Ks[64 * 64];
  __shared__ __align__(16) unsigned short Vs[64 * 64];   // transposed [d][kt]
  __shared__ __align__(16) unsigned short Ps[4][32 * 64];
  __shared__ float rps[1024];                            // rel_pos[h,:]*log2e

  const int tid = threadIdx.x;
  const int wave = tid >> 6, lane = tid & 63;
  const int q = lane >> 4, c = lane & 15;

  const int lid = blockIdx.x + (blockIdx.y << 3);
  const int xq = lid & 7, y = lid >> 3;
  const int qt = (y & 32) ? (7 - xq) : xq;
  const int b = y >> 4, h = y & 15;

  const unsigned short* qg = qkv + (size_t)b * 1024 * 3072 + h * 64;
  const unsigned short* kg = qg + 1024;
  const unsigned short* vg = qg + 2048;

  #pragma unroll
  for (int i = 0; i < 4; i++) {
    const int idx = tid + i * 256;
    rps[idx & 1023] = rel_pos[h * 2048 + (idx & 1023)] * 1.44269504f;
  }

  const int sr  = tid >> 3;
  const int cg8 = ((tid & 7) ^ (sr & 7)) << 3;
  #pragma unroll
  for (int it = 0; it < 4; it++)
    cp16(qg + (size_t)(qt * 128 + sr + it * 32) * 3072 + cg8, &Qs[(tid + it * 256) * 8]);
  __syncthreads();

  bf16x8 qf[2][2];
  #pragma unroll
  for (int mt = 0; mt < 2; mt++)
    #pragma unroll
    for (int ks = 0; ks < 2; ks++)
      qf[mt][ks] = *(const bf16x8*)&Qs[(wave*32 + mt*16 + c)*64 + ((((ks<<2)+q) ^ (c & 7)) << 3)];

  const f32x4 fzero = {0.f, 0.f, 0.f, 0.f};
  f32x4 O[2][4];
  float l_i[2][4];
  #pragma unroll
  for (int mt = 0; mt < 2; mt++) {
    #pragma unroll
    for (int r = 0; r < 4; r++) l_i[mt][r] = 0.f;
    #pragma unroll
    for (int dt = 0; dt < 4; dt++) O[mt][dt] = fzero;
  }

  unsigned short* Pw = &Ps[wave][0];
  const int i_base = qt * 128 + wave * 32;
  const int vrow = tid & 63, d0 = (tid >> 6) << 4;
  const int vchunk = vrow >> 3, vlo = vrow & 7;

  const float sc = 0.125f * 1.44269504f;
  const int kdiag = qt << 1;
  const int nkt = (qt + 1) * 2;

  for (int kt = 0; kt < nkt; kt++) {
    __syncthreads();
    cp16(kg + (size_t)(kt * 64 + sr) * 3072 + cg8, &Ks[tid * 8]);
    cp16(kg + (size_t)(kt * 64 + sr + 32) * 3072 + cg8, &Ks[(tid + 256) * 8]);
    {
      union { int4 v; unsigned short u[8]; } va, vb2;
      const unsigned short* vrp = vg + (size_t)(kt * 64 + vrow) * 3072 + d0;
      va.v  = *(const int4*)vrp;
      vb2.v = *(const int4*)(vrp + 8);
      #pragma unroll
      for (int j = 0; j < 8; j++) {
        const int pos = ((vchunk ^ j) << 3) + vlo;
        Vs[(d0 + j) * 64 + pos]     = va.u[j];
        Vs[(d0 + 8 + j) * 64 + pos] = vb2.u[j];
      }
    }
    __syncthreads();

    f32x4 S[2][4];
    #pragma unroll
    for (int mt = 0; mt < 2; mt++)
      #pragma unroll
      for (int nt = 0; nt < 4; nt++) S[mt][nt] = fzero;
    #pragma unroll
    for (int ks = 0; ks < 2; ks++) {
      const int sw = (((ks << 2) + q) ^ (c & 7)) << 3;
      bf16x8 kb[4];
      #pragma unroll
      for (int nt = 0; nt < 4; nt++) kb[nt] = *(const bf16x8*)&Ks[(nt*16 + c)*64 + sw];
      #pragma unroll
      for (int mt = 0; mt < 2; mt++)
        #pragma unroll
        for (int nt = 0; nt < 4; nt++)
          S[mt][nt] = __builtin_amdgcn_mfma_f32_16x16x32_bf16(qf[mt][ks], kb[nt], S[mt][nt], 0, 0, 0);
    }

    if (kt < kdiag) {
      #pragma unroll
      for (int mt = 0; mt < 2; mt++) {
        #pragma unroll
        for (int r = 0; r < 4; r++) {
          const int i_ = i_base + mt * 16 + q * 4 + r;
          const int prow = (mt * 16 + q * 4 + r) * 64;
          const int rsw  = (q * 4 + r) & 7;
          float s = 0.f;
          #pragma unroll
          for (int nt = 0; nt < 4; nt++) {
            const int j_ = kt * 64 + nt * 16 + c;
            const float p = exp2f(fmaf(S[mt][nt][r], sc, rps[i_ - j_]));
            s += p;
            Pw[prow + ((((nt << 1) + (c >> 3)) ^ rsw) << 3) + (c & 7)] = f2bf_fast(p);
          }
          l_i[mt][r] += s;
        }
      }
    } else {
      #pragma unroll
      for (int mt = 0; mt < 2; mt++) {
        #pragma unroll
        for (int r = 0; r < 4; r++) {
          const int i_ = i_base + mt * 16 + q * 4 + r;
          const int prow = (mt * 16 + q * 4 + r) * 64;
          const int rsw  = (q * 4 + r) & 7;
          float s = 0.f;
          #pragma unroll
          for (int nt = 0; nt < 4; nt++) {
            const int j_ = kt * 64 + nt * 16 + c;
            const int d_ = i_ - j_;
            const float p = (d_ >= 0)
                ? exp2f(fmaf(S[mt][nt][r], sc, rps[d_ & 1023])) : 0.f;
            s += p;
            Pw[prow + ((((nt << 1) + (c >> 3)) ^ rsw) << 3) + (c & 7)] = f2bf_fast(p);
          }
          l_i[mt][r] += s;
        }
      }
    }

    asm volatile("s_waitcnt lgkmcnt(0)" ::: "memory");

    #pragma unroll
    for (int ks = 0; ks < 2; ks++) {
      const int sw = (((ks << 2) + q) ^ (c & 7)) << 3;
      bf16x8 pa[2], vb[4];
      #pragma unroll
      for (int mt = 0; mt < 2; mt++) pa[mt] = *(const bf16x8*)&Pw[(mt*16 + c)*64 + sw];
      #pragma unroll
      for (int dt = 0; dt < 4; dt++) vb[dt] = *(const bf16x8*)&Vs[(dt*16 + c)*64 + sw];
      #pragma unroll
      for (int mt = 0; mt < 2; mt++)
        #pragma unroll
        for (int dt = 0; dt < 4; dt++)
          O[mt][dt] = __builtin_amdgcn_mfma_f32_16x16x32_bf16(pa[mt], vb[dt], O[mt][dt], 0, 0, 0);
    }
  }

  #pragma unroll
  for (int mt = 0; mt < 2; mt++) {
    #pragma unroll
    for (int r = 0; r < 4; r++) {
      float l = l_i[mt][r];
      l += __shfl_xor(l, 1, 64);
      l += __shfl_xor(l, 2, 64);
      l += __shfl_xor(l, 4, 64);
      l += __shfl_xor(l, 8, 64);
      const float inv = 1.0f / l;
      const int i_ = i_base + mt * 16 + q * 4 + r;
      unsigned short* orow = o + (size_t)(b * 1024 + i_) * 1024 + h * 64 + c;
      #pragma unroll
      for (int dt = 0; dt < 4; dt++) orow[dt * 16] = f2bf(O[mt][dt][r] * inv);
    }
  }
}

// ---------------------------------------------------------------------------
// Launch. Workspace aliased down to ~81 MB (less 0xAA re-poison traffic):
//   xm == xn (xn dead after QKV); hb == qkvb|ob (both dead after out-proj).
// ---------------------------------------------------------------------------
extern "C" void kernel_launch(void* const* d_in, const int* in_sizes, int n_in,
                              void* d_out, int out_size, void* d_ws, size_t ws_size,
                              hipStream_t stream) {
  (void)in_sizes; (void)n_in; (void)out_size; (void)ws_size;
  const float* x    = (const float*)d_in[0];
  const float* rel  = (const float*)d_in[1];
  const float* ipw  = (const float*)d_in[2];
  const float* ipb  = (const float*)d_in[3];
  const float* outw = (const float*)d_in[4];
  const float* outb = (const float*)d_in[5];
  const float* w1   = (const float*)d_in[6];
  const float* b1   = (const float*)d_in[7];
  const float* w2   = (const float*)d_in[8];
  const float* b2   = (const float*)d_in[9];
  const float* ln1g = (const float*)d_in[10];
  const float* ln1b = (const float*)d_in[11];
  const float* ln2g = (const float*)d_in[12];
  const float* ln2b = (const float*)d_in[13];

  // workspace layout (elements), aliased:
  unsigned short* ipw_b  = (unsigned short*)d_ws;            // 3072*1024
  unsigned short* outw_b = ipw_b  + (size_t)3072 * 1024;     // 1024*1024
  unsigned short* w1_b   = outw_b + (size_t)1024 * 1024;     // 4096*1024
  unsigned short* w2_b   = w1_b   + (size_t)4096 * 1024;     // 1024*4096
  unsigned short* xn     = w2_b   + (size_t)1024 * 4096;     // 4096*1024 (also xm)
  unsigned short* qkvb   = xn     + (size_t)4096 * 1024;     // 4096*3072 ┐
  unsigned short* ob     = qkvb   + (size_t)4096 * 3072;     // 4096*1024 ┴ hb aliases both
  unsigned short* hb     = qkvb;                             // 4096*4096 (after out-proj)
  unsigned short* xm     = xn;                               // after QKV consumed xn
  float*          x2     = (float*)(ob + (size_t)4096 * 1024);  // 4096*1024 f32
  // total = 81 MB

  // fused: weight converts + ln1 + seed x2 = x + outb
  cvt_ln1<<<16384, 256, 0, stream>>>(ipw, outw, w1, w2, ipw_b, outw_b, w1_b, w2_b,
                                     x, ln1g, ln1b, xn, outb, x2);

  // QKV proj
  gemm_bt<0><<<dim3(32, 24), 256, 0, stream>>>(xn, ipw_b, ipb, qkvb, 3072, 1024);

  attn_flash<<<dim3(8, 64), 256, 0, stream>>>(qkvb, rel, ob);

  // attn out proj: x2 += ob @ outw^T  (split-K=2, atomic)
  gemm_bt_splitk<<<dim3(32, 8, 2), 256, 0, stream>>>(ob, outw_b, x2, 1024, 1024);

  // ln2 + seed d_out = x2 + b2
  ln_bf16_seed<<<4096, 256, 0, stream>>>(x2, ln2g, ln2b, xm, b2, (float*)d_out);

  // MLP up (writes hb, aliasing qkvb|ob — both dead now)
  gemm_bt<2><<<dim3(32, 32), 256, 0, stream>>>(xm, w1_b, b1, hb, 4096, 1024);

  // MLP down: d_out += hb @ w2^T  (split-K=2, atomic)
  gemm_bt_splitk<<<dim3(32, 8, 2), 256, 0, stream>>>(hb, w2_b, (float*)d_out, 1024, 4096);
}